// Round 1
// baseline (1699.290 us; speedup 1.0000x reference)
//
#include <hip/hip_runtime.h>

// Problem constants (BatchConv2DLayer: per-sample 3x3 conv, stride 1, pad 1)
#define BB   32   // batch
#define CI   32   // in channels
#define CO   32   // out channels
#define HH   256
#define WW   256
#define HT   16           // output rows per block
#define XR   (HT + 2)     // staged x rows (with h halo)
#define LROW 264          // LDS row stride in floats (16B-aligned rows: 264*4=1056)

// Block: 256 threads. Thread t: wg = t&63 -> 4 output cols at w0=4*wg;
// rp = t>>6 -> 4 output rows at r0=4*rp. So block covers 16 rows x 256 cols
// for one (b, co). Per-ci staging of x rows into LDS; weights broadcast from LDS.
__global__ __launch_bounds__(256)
void conv3x3_kernel(const float* __restrict__ x,
                    const float* __restrict__ wgt,
                    const float* __restrict__ bias,
                    float* __restrict__ out) {
    __shared__ float xs[XR * LROW];
    __shared__ float ws[CI * 9];

    const int co = blockIdx.x;
    const int ht = blockIdx.y;
    const int b  = blockIdx.z;
    const int tid = threadIdx.x;
    const int h0 = ht * HT;

    // Stage all 288 weights for (b, co) into LDS.
    for (int i = tid; i < CI * 9; i += 256) {
        ws[i] = wgt[((size_t)(b * CO + co) * CI) * 9 + i];
    }
    // Zero the pad columns once: cols 0..3 (left, col c <-> global w = c-4,
    // so col 3 is the w=-1 zero pad) and cols 260..263 (right, w=256 pad).
    for (int i = tid; i < XR * 8; i += 256) {
        int row = i >> 3;
        int c   = i & 7;
        int col = (c < 4) ? c : (256 + c);
        xs[row * LROW + col] = 0.0f;
    }

    const int wg = tid & 63;   // 64 col-groups of 4
    const int rp = tid >> 6;   // 4 row-groups of 4
    const int w0 = wg * 4;
    const int r0 = rp * 4;

    float acc[4][4];
    #pragma unroll
    for (int d = 0; d < 4; ++d)
        #pragma unroll
        for (int j = 0; j < 4; ++j) acc[d][j] = 0.0f;

    const float* xb = x + (size_t)(b * CI) * HH * WW;

    for (int ci = 0; ci < CI; ++ci) {
        __syncthreads();  // protect previous iteration's reads
        // Stage rows h0-1 .. h0+16 of x[b][ci] into LDS (cols 4..259).
        const float* xsrc = xb + (size_t)ci * HH * WW;
        for (int i = tid; i < XR * 64; i += 256) {
            int row = i >> 6;
            int cq  = i & 63;
            int gh  = h0 - 1 + row;
            float4 v = make_float4(0.0f, 0.0f, 0.0f, 0.0f);
            if (gh >= 0 && gh < HH) {
                v = *(const float4*)(xsrc + (size_t)gh * WW + cq * 4);
            }
            *(float4*)(&xs[row * LROW + 4 + cq * 4]) = v;
        }
        __syncthreads();

        float wk[9];
        #pragma unroll
        for (int k = 0; k < 9; ++k) wk[k] = ws[ci * 9 + k];

        // Output row r (local) uses xs rows r..r+2. This thread: rows r0..r0+3,
        // so xs rows r0..r0+5. xs col c <-> global w = c-4.
        #pragma unroll
        for (int xr = 0; xr < 6; ++xr) {
            const float* rowp = &xs[(r0 + xr) * LROW + w0];  // 16B aligned
            float xv[12];
            #pragma unroll
            for (int q = 0; q < 3; ++q) {
                float4 v = *(const float4*)(rowp + 4 * q);
                xv[4*q+0] = v.x; xv[4*q+1] = v.y; xv[4*q+2] = v.z; xv[4*q+3] = v.w;
            }
            // xv[i] <-> global w = w0 + i - 4. Output (r0+dr, w0+j), tap kw
            // needs w = w0+j+kw-1 -> xv[j+kw+3] (range 3..9).
            #pragma unroll
            for (int dr = 0; dr < 4; ++dr) {
                const int kh = xr - dr;
                if (kh < 0 || kh > 2) continue;
                #pragma unroll
                for (int kw = 0; kw < 3; ++kw) {
                    const float wv = wk[kh * 3 + kw];
                    #pragma unroll
                    for (int j = 0; j < 4; ++j) {
                        acc[dr][j] += xv[j + kw + 3] * wv;
                    }
                }
            }
        }
    }

    // Epilogue: add bias, store 4 rows x float4.
    const float bv = bias[b * CO + co];
    float* ob = out + ((size_t)(b * CO + co) * HH + (h0 + r0)) * WW + w0;
    #pragma unroll
    for (int dr = 0; dr < 4; ++dr) {
        float4 o;
        o.x = acc[dr][0] + bv;
        o.y = acc[dr][1] + bv;
        o.z = acc[dr][2] + bv;
        o.w = acc[dr][3] + bv;
        *(float4*)(ob + (size_t)dr * WW) = o;
    }
}

extern "C" void kernel_launch(void* const* d_in, const int* in_sizes, int n_in,
                              void* d_out, int out_size, void* d_ws, size_t ws_size,
                              hipStream_t stream) {
    const float* x    = (const float*)d_in[0];
    const float* wgt  = (const float*)d_in[1];
    const float* bias = (const float*)d_in[2];
    float* out        = (float*)d_out;

    dim3 grid(CO, HH / HT, BB);  // (co, h-tile, b)
    dim3 block(256);
    hipLaunchKernelGGL(conv3x3_kernel, grid, block, 0, stream,
                       x, wgt, bias, out);
}

// Round 2
// 555.437 us; speedup vs baseline: 3.0594x; 3.0594x over previous
//
#include <hip/hip_runtime.h>

// BatchConv2DLayer: per-sample 3x3 conv, stride 1, pad 1, fp32 in/out.
// Strategy: NCHW->NHWC bf16 transpose into d_ws, then implicit-GEMM conv
// with mfma_f32_16x16x32_bf16 (M=co=16/wave-half, N=16 pixels, K=32 ci),
// 9 taps accumulated. Falls back to direct fp32 conv if ws too small.

#define BB 32
#define CI 32
#define CO 32
#define HH 256
#define WW 256

typedef unsigned int uint;
using short8  = __attribute__((ext_vector_type(8))) short;
using float4v = __attribute__((ext_vector_type(4))) float;

__device__ inline unsigned short f2bf(float f) {
    union { float f; uint u; } c; c.f = f;
    uint r = c.u + 0x7fffu + ((c.u >> 16) & 1u);   // round-to-nearest-even
    return (unsigned short)(r >> 16);
}

// ---------------------------------------------------------------------------
// Kernel 1: x [b][ci][h][w] fp32  ->  xt [b][h][w][ci] bf16 (into d_ws)
// Block = one (b,h): 32ci x 256w. LDS tile[ci][w] fp32, row stride 260
// (260*4 % 16 == 0 for float4 writes; bank stride 260%32=4, reads 2-way free).
// ---------------------------------------------------------------------------
__global__ __launch_bounds__(256)
void transpose_kernel(const float* __restrict__ x,
                      unsigned short* __restrict__ xt) {
    __shared__ float tile[CI * 260];
    const int h = blockIdx.x;
    const int b = blockIdx.y;
    const int t = threadIdx.x;

    const float* xp = x + (size_t)b * CI * HH * WW + (size_t)h * WW;
    #pragma unroll
    for (int i = 0; i < 8; ++i) {
        int idx = t + 256 * i;          // 0..2047
        int w4  = idx & 63;             // float4 index along w
        int ci  = idx >> 6;
        float4 v = *(const float4*)(xp + (size_t)ci * HH * WW + w4 * 4);
        *(float4*)(&tile[ci * 260 + w4 * 4]) = v;
    }
    __syncthreads();

    // Thread t emits pixel w=t: 32 ci as bf16 packed into 16 dwords.
    const int w = t;
    uint dw[16];
    #pragma unroll
    for (int j = 0; j < 16; ++j) {
        uint lo = f2bf(tile[(2 * j) * 260 + w]);
        uint hi = f2bf(tile[(2 * j + 1) * 260 + w]);
        dw[j] = lo | (hi << 16);
    }
    unsigned short* op = xt + (((size_t)(b * HH + h)) * WW + w) * CI;
    #pragma unroll
    for (int q = 0; q < 4; ++q) {
        uint4 v = make_uint4(dw[4*q+0], dw[4*q+1], dw[4*q+2], dw[4*q+3]);
        *(uint4*)(op + q * 8) = v;
    }
}

// ---------------------------------------------------------------------------
// Kernel 2: implicit-GEMM conv. Block = (b, 8-row x 32-col output tile),
// 256 threads = 4 waves. LDS: x tile 10x34 pixels x 32ci bf16 (21.8KB) +
// all 32co x 9tap x 32ci weights bf16 (18KB). One barrier, then per wave:
// 8 pixel-groups x 9 taps x (ds_read_b128 B-frag + mfma).
// mfma_f32_16x16x32_bf16 layouts (guide §3, m89/m91-verified):
//   A[m=lane&15][k=(lane>>4)*8+j]  (m=co, k=ci)
//   B[k=(lane>>4)*8+j][n=lane&15]  (n=pixel)
//   D: col(n)=lane&15, row(m)=(lane>>4)*4+reg
// ---------------------------------------------------------------------------
#define TH 8
#define TW 32
#define XR (TH + 2)
#define XC (TW + 2)

__global__ __launch_bounds__(256)
void conv_mfma_kernel(const unsigned short* __restrict__ xt,
                      const float* __restrict__ wgt,
                      const float* __restrict__ bias,
                      float* __restrict__ out) {
    __shared__ unsigned short xs[XR * XC * CI];   // [pix][ci], pix = r*34+c
    __shared__ unsigned short ws[CO * 9 * CI];    // [co][tap][ci]

    const int tw = blockIdx.x;   // 0..7
    const int th = blockIdx.y;   // 0..31
    const int b  = blockIdx.z;
    const int t  = threadIdx.x;
    const int h0 = th * TH, w0 = tw * TW;

    // Stage weights for this b: 32co*32ci*9 fp32 -> bf16 [co][tap][ci].
    const float* wp = wgt + (size_t)(b * CO) * CI * 9;
    for (int i = t; i < CO * CI * 9; i += 256) {
        int co  = i / (CI * 9);
        int rem = i - co * (CI * 9);
        int ci  = rem / 9;
        int tp  = rem - ci * 9;
        ws[(co * 9 + tp) * CI + ci] = f2bf(wp[i]);
    }
    // Stage x tile (rows h0-1..h0+8, cols w0-1..w0+32), zero-pad OOB.
    for (int i = t; i < XR * XC * 4; i += 256) {
        int q   = i & 3;          // 16B quad within pixel's 64B
        int pix = i >> 2;
        int r   = pix / XC;
        int c   = pix - r * XC;
        int h   = h0 - 1 + r;
        int w   = w0 - 1 + c;
        uint4 v = make_uint4(0, 0, 0, 0);
        if (h >= 0 && h < HH && w >= 0 && w < WW) {
            v = *(const uint4*)(xt + (((size_t)(b * HH + h)) * WW + w) * CI + q * 8);
        }
        *(uint4*)(&xs[pix * CI + q * 8]) = v;
    }
    __syncthreads();

    const int wv  = t >> 6;
    const int l   = t & 63;
    const int lp  = l & 15;            // A:m(co offset) == B:n(pixel)
    const int lq  = l >> 4;            // quad -> k = lq*8+j
    const int co0 = (wv & 1) * 16;     // wave's co half
    const int gb  = (wv >> 1) * 8;     // wave's 8 pixel-groups

    short8 A[9];
    #pragma unroll
    for (int tp = 0; tp < 9; ++tp)
        A[tp] = *(const short8*)(&ws[((co0 + lp) * 9 + tp) * CI + lq * 8]);

    float4v acc[8];
    #pragma unroll
    for (int g = 0; g < 8; ++g) acc[g] = {0.f, 0.f, 0.f, 0.f};

    #pragma unroll
    for (int g = 0; g < 8; ++g) {
        const int gg = gb + g;
        const int r  = gg >> 1;          // local output row
        const int c0 = (gg & 1) * 16;    // local output col base
        #pragma unroll
        for (int kh = 0; kh < 3; ++kh) {
            #pragma unroll
            for (int kw = 0; kw < 3; ++kw) {
                // x row (r+kh) <-> global h0+r+kh-1; col c0+lp+kw <-> w0+c0+lp+kw-1
                short8 Bf = *(const short8*)(
                    &xs[((r + kh) * XC + (c0 + lp + kw)) * CI + lq * 8]);
                acc[g] = __builtin_amdgcn_mfma_f32_16x16x32_bf16(
                    A[kh * 3 + kw], Bf, acc[g], 0, 0, 0);
            }
        }
    }

    // Epilogue: D row = co0 + lq*4 + v, col(pixel) = lp.
    float bv[4];
    #pragma unroll
    for (int v = 0; v < 4; ++v) bv[v] = bias[b * CO + co0 + lq * 4 + v];

    #pragma unroll
    for (int g = 0; g < 8; ++g) {
        const int gg = gb + g;
        const int r  = gg >> 1;
        const int c0 = (gg & 1) * 16;
        const int h  = h0 + r;
        const int wpix = w0 + c0 + lp;
        #pragma unroll
        for (int v = 0; v < 4; ++v) {
            const int co = co0 + lq * 4 + v;
            out[(((size_t)(b * CO + co)) * HH + h) * WW + wpix] = acc[g][v] + bv[v];
        }
    }
}

// ---------------------------------------------------------------------------
// Fallback (round-1 direct fp32 conv) if ws is too small for the bf16 NHWC copy.
// ---------------------------------------------------------------------------
#define FHT 16
#define FXR (FHT + 2)
#define LROW 264

__global__ __launch_bounds__(256)
void conv3x3_fallback(const float* __restrict__ x,
                      const float* __restrict__ wgt,
                      const float* __restrict__ bias,
                      float* __restrict__ out) {
    __shared__ float xs[FXR * LROW];
    __shared__ float wsh[CI * 9];
    const int co = blockIdx.x;
    const int ht = blockIdx.y;
    const int b  = blockIdx.z;
    const int tid = threadIdx.x;
    const int h0 = ht * FHT;
    for (int i = tid; i < CI * 9; i += 256)
        wsh[i] = wgt[((size_t)(b * CO + co) * CI) * 9 + i];
    for (int i = tid; i < FXR * 8; i += 256) {
        int row = i >> 3; int c = i & 7;
        int col = (c < 4) ? c : (256 + c);
        xs[row * LROW + col] = 0.0f;
    }
    const int wg = tid & 63, rp = tid >> 6;
    const int w0 = wg * 4, r0 = rp * 4;
    float acc[4][4];
    #pragma unroll
    for (int d = 0; d < 4; ++d)
        #pragma unroll
        for (int j = 0; j < 4; ++j) acc[d][j] = 0.0f;
    const float* xb = x + (size_t)(b * CI) * HH * WW;
    for (int ci = 0; ci < CI; ++ci) {
        __syncthreads();
        const float* xsrc = xb + (size_t)ci * HH * WW;
        for (int i = tid; i < FXR * 64; i += 256) {
            int row = i >> 6; int cq = i & 63;
            int gh = h0 - 1 + row;
            float4 v = make_float4(0.f, 0.f, 0.f, 0.f);
            if (gh >= 0 && gh < HH)
                v = *(const float4*)(xsrc + (size_t)gh * WW + cq * 4);
            *(float4*)(&xs[row * LROW + 4 + cq * 4]) = v;
        }
        __syncthreads();
        float wk[9];
        #pragma unroll
        for (int k = 0; k < 9; ++k) wk[k] = wsh[ci * 9 + k];
        #pragma unroll
        for (int xr = 0; xr < 6; ++xr) {
            const float* rowp = &xs[(r0 + xr) * LROW + w0];
            float xv[12];
            #pragma unroll
            for (int q = 0; q < 3; ++q) {
                float4 v = *(const float4*)(rowp + 4 * q);
                xv[4*q+0] = v.x; xv[4*q+1] = v.y; xv[4*q+2] = v.z; xv[4*q+3] = v.w;
            }
            #pragma unroll
            for (int dr = 0; dr < 4; ++dr) {
                const int kh = xr - dr;
                if (kh < 0 || kh > 2) continue;
                #pragma unroll
                for (int kw = 0; kw < 3; ++kw) {
                    const float wvv = wk[kh * 3 + kw];
                    #pragma unroll
                    for (int j = 0; j < 4; ++j)
                        acc[dr][j] += xv[j + kw + 3] * wvv;
                }
            }
        }
    }
    const float bv = bias[b * CO + co];
    float* ob = out + ((size_t)(b * CO + co) * HH + (h0 + r0)) * WW + w0;
    #pragma unroll
    for (int dr = 0; dr < 4; ++dr) {
        float4 o;
        o.x = acc[dr][0] + bv; o.y = acc[dr][1] + bv;
        o.z = acc[dr][2] + bv; o.w = acc[dr][3] + bv;
        *(float4*)(ob + (size_t)dr * WW) = o;
    }
}

extern "C" void kernel_launch(void* const* d_in, const int* in_sizes, int n_in,
                              void* d_out, int out_size, void* d_ws, size_t ws_size,
                              hipStream_t stream) {
    const float* x    = (const float*)d_in[0];
    const float* wgt  = (const float*)d_in[1];
    const float* bias = (const float*)d_in[2];
    float* out        = (float*)d_out;

    const size_t need = (size_t)BB * HH * WW * CI * sizeof(unsigned short); // 128MB
    if (ws_size >= need) {
        unsigned short* xt = (unsigned short*)d_ws;
        hipLaunchKernelGGL(transpose_kernel, dim3(HH, BB), dim3(256), 0, stream,
                           x, xt);
        hipLaunchKernelGGL(conv_mfma_kernel, dim3(WW / TW, HH / TH, BB), dim3(256),
                           0, stream, xt, wgt, bias, out);
    } else {
        hipLaunchKernelGGL(conv3x3_fallback, dim3(CO, HH / FHT, BB), dim3(256),
                           0, stream, x, wgt, bias, out);
    }
}